// Round 7
// baseline (1068.669 us; speedup 1.0000x reference)
//
#include <hip/hip_runtime.h>
#include <hip/hip_bf16.h>

// Problem constants
#define NB    65536      // batch rows
#define KDIM  1024       // reduction dim for all projections
#define NDIM  1024       // output dim per projection

// 256x256 GEMM geometry, BK=64, double-buffered
#define BM 256
#define BN 256
#define BK 64
#define NT (KDIM / BK)   // 16 K-tiles

typedef float f32x4 __attribute__((ext_vector_type(4)));
typedef short short8 __attribute__((ext_vector_type(8)));
typedef unsigned short ushort8v __attribute__((ext_vector_type(8)));

static __device__ __forceinline__ unsigned short f2bf(float f) {
    union { float f; unsigned u; } v; v.f = f;
    unsigned r = v.u + 0x7FFFu + ((v.u >> 16) & 1u);
    return (unsigned short)(r >> 16);
}
static __device__ __forceinline__ float bf2f(unsigned short h) {
    union { unsigned u; float f; } v; v.u = ((unsigned)h) << 16;
    return v.f;
}

// async global->LDS, 16B per lane. LDS dest = wave-uniform base + lane*16.
static __device__ __forceinline__ void gload16(const unsigned short* g, unsigned short* l) {
    __builtin_amdgcn_global_load_lds(
        (const __attribute__((address_space(1))) unsigned int*)g,
        (__attribute__((address_space(3))) unsigned int*)l, 16, 0, 0);
}

// ---------------------------------------------------------------------------
// fp32 -> bf16 convert, grid-stride, 4 elems/thread/iter
// ---------------------------------------------------------------------------
__global__ __launch_bounds__(256) void f32_to_bf16_k(
    const float* __restrict__ s, unsigned short* __restrict__ d, int n4)
{
    const int stride = gridDim.x * 256;
    for (int i = blockIdx.x * 256 + threadIdx.x; i < n4; i += stride) {
        float4 v = reinterpret_cast<const float4*>(s)[i];
        ushort4 o;
        o.x = f2bf(v.x); o.y = f2bf(v.y); o.z = f2bf(v.z); o.w = f2bf(v.w);
        reinterpret_cast<ushort4*>(d)[i] = o;
    }
}

// ---------------------------------------------------------------------------
// 256x256 GEMM: C[M,N] = A[M,K] @ W[N,K]^T (+bias), BK=64, m97-style loop.
// 512 threads = 8 waves (2 Mwaves x 4 Nwaves); per-wave output 128x64.
// LDS 128 KB: 2 buffers x (A 32KB + B 32KB), FRAGMENT-ORDERED 1KB sub-blocks
// (per-lane pre-swizzled global source + linear gload_lds dest): every
// ds_read_b128 is uniform_base + lane*16 -> zero bank conflicts (verified
// r5/r6: SQ_LDS_BANK_CONFLICT = 0).
// Per K-tile: { stage(t+1)->other buf (8 gloads); 24 ds_reads + 64 MFMA
// (compiler-scheduled counted lgkm waits -- m97 mechanism); vmcnt(0);
// barrier }. One barrier + one vmcnt per tile; r5/r6 showed the extra
// phase machinery (8 barriers + counted vmcnt) buys nothing at this shape.
// Overwrite safety: stage at t+1 targets buf(t^1), issued after tile-t's
// trailing barrier at which every wave has consumed its reads of buf(t^1)
// from tile t-1 (lgkm-before-MFMA precedes barrier arrival).
//
// Epilogue: acc -> LDS bounce (tiles dead post-loop) -> coalesced full-line
// stores. Fixes the 2.2x write amplification of scalar 2B stores (r6:
// WRITE_SIZE 280 MB vs 128 ideal).
// ---------------------------------------------------------------------------
template<int OUT_F32>
__global__ __launch_bounds__(512, 2) void gemm256(
    const unsigned short* __restrict__ Ap, const unsigned short* __restrict__ Wp,
    const float* __restrict__ bias, void* __restrict__ Cptr)
{
    constexpr int N = NDIM;
    constexpr int GN = NDIM / BN;            // 4 col tiles
    // [buf][A|B][f-block(16 rows)][2KB = ks*512 + lane*8 shorts]
    __shared__ alignas(16) unsigned short lds[2][2][16][1024];

    const int t    = threadIdx.x;
    const int lane = t & 63;
    const int wid  = t >> 6;                 // 0..7
    const int wm   = wid >> 2;               // 0..1  (128 rows each)
    const int wn   = wid & 3;                // 0..3  (64 cols each)

    // XCD-chunked swizzle (nwg = 1024, % 8 == 0)
    const int nwg  = gridDim.x;
    const int cpx  = nwg >> 3;
    const int orig = blockIdx.x;
    const int wgid = (orig & 7) * cpx + (orig >> 3);
    const int bn0  = (wgid & (GN - 1)) * BN;
    const int bm0  = (wgid / GN) * BM;

    // per-lane fragment offset within a block's 16-row x 32-col source region
    const size_t aoff = (size_t)(lane & 15) * KDIM + (lane >> 4) * 8;

#define LDA_(BUF, MI, KS) \
    (*reinterpret_cast<const short8*>(&lds[BUF][0][wm * 8 + (MI)][(KS) * 512 + lane * 8]))
#define LDB_(BUF, NI, KS) \
    (*reinterpret_cast<const short8*>(&lds[BUF][1][wn * 4 + (NI)][(KS) * 512 + lane * 8]))

    // stage K-tile TAU (A and B, both ks halves) into buffer SLOT: 8 gloads/wave
#define STAGE_(TAU, SLOT) do {                                                  \
        _Pragma("unroll")                                                       \
        for (int _ab = 0; _ab < 2; ++_ab) {                                     \
            const unsigned short* _b = _ab ? Wp : Ap;                           \
            int _r0 = _ab ? bn0 : bm0;                                          \
            _Pragma("unroll")                                                   \
            for (int _j = 0; _j < 2; ++_j) {                                    \
                int _f = wid * 2 + _j;                                          \
                _Pragma("unroll")                                               \
                for (int _ks = 0; _ks < 2; ++_ks)                               \
                    gload16(_b + (size_t)(_r0 + _f * 16) * KDIM                 \
                                + (TAU) * BK + _ks * 32 + aoff,                 \
                            &lds[SLOT][_ab][_f][_ks * 512]);                    \
            }                                                                   \
        }                                                                       \
    } while (0)

    f32x4 acc[8][4];
#pragma unroll
    for (int mi = 0; mi < 8; ++mi)
#pragma unroll
        for (int ni = 0; ni < 4; ++ni)
            acc[mi][ni] = (f32x4){0.f, 0.f, 0.f, 0.f};

    // prologue
    STAGE_(0, 0);
    asm volatile("s_waitcnt vmcnt(0)" ::: "memory");
    __builtin_amdgcn_s_barrier();

#pragma unroll 1
    for (int tt = 0; tt < NT; ++tt) {
        const int buf = tt & 1;
        if (tt + 1 < NT) STAGE_(tt + 1, buf ^ 1);   // DMA flows under compute

#pragma unroll
        for (int ks = 0; ks < 2; ++ks) {
            short8 af[8], bq[4];
#pragma unroll
            for (int mi = 0; mi < 8; ++mi) af[mi] = LDA_(buf, mi, ks);
#pragma unroll
            for (int ni = 0; ni < 4; ++ni) bq[ni] = LDB_(buf, ni, ks);
            __builtin_amdgcn_s_setprio(1);
#pragma unroll
            for (int mi = 0; mi < 8; ++mi)
#pragma unroll
                for (int ni = 0; ni < 4; ++ni)
                    acc[mi][ni] = __builtin_amdgcn_mfma_f32_16x16x32_bf16(
                        af[mi], bq[ni], acc[mi][ni], 0, 0, 0);
            __builtin_amdgcn_s_setprio(0);
        }
        asm volatile("s_waitcnt vmcnt(0)" ::: "memory");  // next tile landed
        __builtin_amdgcn_s_barrier();
    }

    // ------------- epilogue: LDS bounce -> coalesced full-line stores -------
    // acc fragment: D row = (lane>>4)*4 + r, col = lane&15  [m89-verified]
    const int crow = (lane >> 4) * 4;
    const int ccol = lane & 15;

    if (OUT_F32) {
        float* Cf = (float*)Cptr;
        float* bbf = reinterpret_cast<float*>(&lds[0][0][0][0]);
        float bv[4];
#pragma unroll
        for (int ni = 0; ni < 4; ++ni)
            bv[ni] = bias[bn0 + wn * 64 + ni * 16 + ccol];
        // 8 passes x 32 rows; stride 268 floats (pad 12 -> row-groups alternate banks)
#pragma unroll
        for (int p = 0; p < 8; ++p) {
            if (wm == (p >> 2)) {
#pragma unroll
                for (int ml = 0; ml < 2; ++ml)
#pragma unroll
                    for (int ni = 0; ni < 4; ++ni)
#pragma unroll
                        for (int r = 0; r < 4; ++r)
                            bbf[(ml * 16 + crow + r) * 268 + wn * 64 + ni * 16 + ccol]
                                = acc[(p & 3) * 2 + ml][ni][r] + bv[ni];
            }
            __syncthreads();
#pragma unroll
            for (int it = 0; it < 4; ++it) {
                int lrow = wid * 4 + it;                      // 0..31
                f32x4 v = *reinterpret_cast<const f32x4*>(&bbf[lrow * 268 + lane * 4]);
                *reinterpret_cast<f32x4*>(
                    &Cf[(size_t)(bm0 + p * 32 + lrow) * N + bn0 + lane * 4]) = v;
            }
            __syncthreads();
        }
    } else {
        unsigned short* Cb = (unsigned short*)Cptr;
        unsigned short* bb = &lds[0][0][0][0];
        // 4 passes x 64 rows; stride 264 shorts (pad 8)
#pragma unroll
        for (int p = 0; p < 4; ++p) {
            if (wm == (p >> 1)) {
#pragma unroll
                for (int ml = 0; ml < 4; ++ml)
#pragma unroll
                    for (int ni = 0; ni < 4; ++ni)
#pragma unroll
                        for (int r = 0; r < 4; ++r)
                            bb[(ml * 16 + crow + r) * 264 + wn * 64 + ni * 16 + ccol]
                                = f2bf(acc[(p & 1) * 4 + ml][ni][r]);
            }
            __syncthreads();
#pragma unroll
            for (int it = 0; it < 4; ++it) {
                int lrow = wid * 8 + it * 2 + (lane >> 5);    // 0..63
                int lcol = (lane & 31) * 8;
                ushort8v v = *reinterpret_cast<const ushort8v*>(&bb[lrow * 264 + lcol]);
                *reinterpret_cast<ushort8v*>(
                    &Cb[(size_t)(bm0 + p * 64 + lrow) * N + bn0 + lcol]) = v;
            }
            __syncthreads();
        }
    }
#undef LDA_
#undef LDB_
#undef STAGE_
}

// ---------------------------------------------------------------------------
// Per-row attention (unchanged, verified): 1 wave/row, 4 waves/block.
// ---------------------------------------------------------------------------
__global__ __launch_bounds__(256) void attn_k(
    const unsigned short* __restrict__ Qb, const unsigned short* __restrict__ Kb,
    const unsigned short* __restrict__ Vb, unsigned short* __restrict__ Fb)
{
    __shared__ alignas(16) unsigned short KL[4][1024];
    __shared__ alignas(16) unsigned short VL[4][1024];
    const int t = threadIdx.x;
    const int lane = t & 63;
    const int wid = t >> 6;
    const size_t row = (size_t)blockIdx.x * 4 + wid;
    const size_t base = row * 1024;
    const int off = lane * 16;

    ushort8v q0 = *reinterpret_cast<const ushort8v*>(&Qb[base + off]);
    ushort8v q1 = *reinterpret_cast<const ushort8v*>(&Qb[base + off + 8]);
    float qf[16];
#pragma unroll
    for (int j = 0; j < 8; ++j) { qf[j] = bf2f(q0[j]); qf[8 + j] = bf2f(q1[j]); }

    *reinterpret_cast<ushort8v*>(&KL[wid][off])     = *reinterpret_cast<const ushort8v*>(&Kb[base + off]);
    *reinterpret_cast<ushort8v*>(&KL[wid][off + 8]) = *reinterpret_cast<const ushort8v*>(&Kb[base + off + 8]);
    *reinterpret_cast<ushort8v*>(&VL[wid][off])     = *reinterpret_cast<const ushort8v*>(&Vb[base + off]);
    *reinterpret_cast<ushort8v*>(&VL[wid][off + 8]) = *reinterpret_cast<const ushort8v*>(&Vb[base + off + 8]);
    __syncthreads();

    const int sub = lane & 3;
    float s[16];
#pragma unroll
    for (int g = 0; g < 16; ++g) {
        const ushort8v k0 = *reinterpret_cast<const ushort8v*>(&KL[wid][g * 64 + sub * 16]);
        const ushort8v k1 = *reinterpret_cast<const ushort8v*>(&KL[wid][g * 64 + sub * 16 + 8]);
        float acc = 0.f;
#pragma unroll
        for (int j = 0; j < 8; ++j)
            acc += qf[j] * bf2f(k0[j]) + qf[8 + j] * bf2f(k1[j]);
        s[g] = acc;
    }
#pragma unroll
    for (int m = 1; m <= 2; m <<= 1)
#pragma unroll
        for (int g = 0; g < 16; ++g)
            s[g] += __shfl_xor(s[g], m, 64);

    float mx = s[0];
#pragma unroll
    for (int g = 1; g < 16; ++g) mx = fmaxf(mx, s[g]);
    float p[16], denom = 0.f;
#pragma unroll
    for (int g = 0; g < 16; ++g) {
        p[g] = __expf((s[g] - mx) * 0.125f);
        denom += p[g];
    }
    float inv = 1.f / denom;

    float f[16];
#pragma unroll
    for (int j = 0; j < 16; ++j) f[j] = 0.f;
#pragma unroll
    for (int g = 0; g < 16; ++g) {
        float pg = p[g] * inv;
        const ushort8v v0 = *reinterpret_cast<const ushort8v*>(&VL[wid][g * 64 + sub * 16]);
        const ushort8v v1 = *reinterpret_cast<const ushort8v*>(&VL[wid][g * 64 + sub * 16 + 8]);
#pragma unroll
        for (int j = 0; j < 8; ++j) {
            f[j]     += pg * bf2f(v0[j]);
            f[8 + j] += pg * bf2f(v1[j]);
        }
    }
    ushort8v o0, o1;
#pragma unroll
    for (int j = 0; j < 8; ++j) { o0[j] = f2bf(f[j]); o1[j] = f2bf(f[8 + j]); }
    *reinterpret_cast<ushort8v*>(&Fb[base + off])     = o0;
    *reinterpret_cast<ushort8v*>(&Fb[base + off + 8]) = o1;
}

// ---------------------------------------------------------------------------
extern "C" void kernel_launch(void* const* d_in, const int* in_sizes, int n_in,
                              void* d_out, int out_size, void* d_ws, size_t ws_size,
                              hipStream_t stream)
{
    (void)in_sizes; (void)n_in; (void)out_size; (void)ws_size;
    const float* latent = (const float*)d_in[0];
    const float* cond   = (const float*)d_in[1];
    const float* Wq     = (const float*)d_in[2];
    const float* Wk     = (const float*)d_in[3];
    const float* Wv     = (const float*)d_in[4];
    const float* Wout   = (const float*)d_in[5];
    const float* bout   = (const float*)d_in[6];
    float* out = (float*)d_out;

    char* ws = (char*)d_ws;
    const size_t MB = 1ull << 20;
    unsigned short* wqb = (unsigned short*)(ws + 0 * MB);
    unsigned short* wkb = (unsigned short*)(ws + 2 * MB);
    unsigned short* wvb = (unsigned short*)(ws + 4 * MB);
    unsigned short* wob = (unsigned short*)(ws + 6 * MB);
    unsigned short* Qb  = (unsigned short*)(ws + 8 * MB);              // 128 MB, becomes feats
    unsigned short* Kbf = (unsigned short*)(ws + 8 * MB + 128 * MB);   // 128 MB
    unsigned short* Vbf = (unsigned short*)(ws + 8 * MB + 256 * MB);   // 128 MB
    unsigned short* Lb  = (unsigned short*)(ws + 8 * MB + 384 * MB);   // 128 MB latent bf16
    unsigned short* Cb  = (unsigned short*)(ws + 8 * MB + 512 * MB);   // 128 MB cond bf16

    const int wn4 = (KDIM * NDIM) / 4;
    f32_to_bf16_k<<<1024, 256, 0, stream>>>(Wq,   wqb, wn4);
    f32_to_bf16_k<<<1024, 256, 0, stream>>>(Wk,   wkb, wn4);
    f32_to_bf16_k<<<1024, 256, 0, stream>>>(Wv,   wvb, wn4);
    f32_to_bf16_k<<<1024, 256, 0, stream>>>(Wout, wob, wn4);

    const int an4 = (NB * KDIM) / 4;
    f32_to_bf16_k<<<4096, 256, 0, stream>>>(latent, Lb, an4);
    f32_to_bf16_k<<<4096, 256, 0, stream>>>(cond,   Cb, an4);

    const int nblk = (NB / BM) * (NDIM / BN);   // 256 * 4 = 1024
    gemm256<0><<<nblk, 512, 0, stream>>>(Lb, wqb, nullptr, Qb);
    gemm256<0><<<nblk, 512, 0, stream>>>(Cb, wkb, nullptr, Kbf);
    gemm256<0><<<nblk, 512, 0, stream>>>(Cb, wvb, nullptr, Vbf);

    attn_k<<<NB / 4, 256, 0, stream>>>(Qb, Kbf, Vbf, Qb);

    gemm256<1><<<nblk, 512, 0, stream>>>(Qb, wob, bout, out);
}

// Round 8
// 1027.979 us; speedup vs baseline: 1.0396x; 1.0396x over previous
//
#include <hip/hip_runtime.h>
#include <hip/hip_bf16.h>

// Problem constants
#define NB    65536      // batch rows
#define KDIM  1024       // reduction dim for all projections
#define NDIM  1024       // output dim per projection

// 256x256 GEMM geometry, BK=32, quad-buffered ring (depth-3 prefetch)
#define BM 256
#define BN 256
#define BK 32
#define NT (KDIM / BK)   // 32 K-tiles

typedef float f32x4 __attribute__((ext_vector_type(4)));
typedef short short8 __attribute__((ext_vector_type(8)));
typedef unsigned short ushort8v __attribute__((ext_vector_type(8)));

static __device__ __forceinline__ unsigned short f2bf(float f) {
    union { float f; unsigned u; } v; v.f = f;
    unsigned r = v.u + 0x7FFFu + ((v.u >> 16) & 1u);
    return (unsigned short)(r >> 16);
}
static __device__ __forceinline__ float bf2f(unsigned short h) {
    union { unsigned u; float f; } v; v.u = ((unsigned)h) << 16;
    return v.f;
}

// async global->LDS, 16B per lane. LDS dest = wave-uniform base + lane*16.
static __device__ __forceinline__ void gload16(const unsigned short* g, unsigned short* l) {
    __builtin_amdgcn_global_load_lds(
        (const __attribute__((address_space(1))) unsigned int*)g,
        (__attribute__((address_space(3))) unsigned int*)l, 16, 0, 0);
}

// ---------------------------------------------------------------------------
// fp32 -> bf16 convert, grid-stride, 4 elems/thread/iter
// ---------------------------------------------------------------------------
__global__ __launch_bounds__(256) void f32_to_bf16_k(
    const float* __restrict__ s, unsigned short* __restrict__ d, int n4)
{
    const int stride = gridDim.x * 256;
    for (int i = blockIdx.x * 256 + threadIdx.x; i < n4; i += stride) {
        float4 v = reinterpret_cast<const float4*>(s)[i];
        ushort4 o;
        o.x = f2bf(v.x); o.y = f2bf(v.y); o.z = f2bf(v.z); o.w = f2bf(v.w);
        reinterpret_cast<ushort4*>(d)[i] = o;
    }
}

// ---------------------------------------------------------------------------
// 256x256 GEMM, BK=32, QUAD-BUFFER RING with depth-3 prefetch.
// C[M,N] = A[M,K] @ W[N,K]^T (+bias). 512 thr = 8 waves (2 Mw x 4 Nw),
// per-wave output 128x64. LDS 128 KB = 4 slots x (A 16KB + B 16KB),
// fragment-ordered 1KB blocks (zero bank conflicts, verified r5-r7).
//
// THEORY (r7 post-mortem): at 1 block/CU every structure so far exposed
// loaded-system DMA completion latency (~4000+ cyc/tile) because the
// issue->wait distance was <= 1 tile. Ring schedule per tile t:
//   { STAGE(t+3) -> slot (t+3)&3   [4 gloads/wave, program order]
//     s_waitcnt vmcnt(12)          [retires exactly stage(t): the 12
//                                   newer loads are stages t+1,t+2,t+3]
//     s_barrier                    [collectivize per-wave vmcnt guarantee]
//     12 ds_read_b128 + 32 MFMA/wave  [compiler-counted lgkm waits]
//     s_barrier }                  [reads consumed (into regs, pre-MFMA)
//                                   before next iter's stage overwrites
//                                   slot (t+4)&3 == t&3]
// Issue->wait distance = 3 tiles (~4500-5500 cyc) >> loaded DMA latency.
// Prologue stages tiles 0,1,2; tail clamps TAU to NT-1 (re-stages real
// data into dead slots: addresses valid, vmcnt cadence preserved).
//
// Epilogue: acc -> LDS bounce -> full-line stores (r7-verified: WRITE_SIZE
// exact-ideal), pass count halved vs r7 (2 bf16 / 4 fp32).
// ---------------------------------------------------------------------------
template<int OUT_F32>
__global__ __launch_bounds__(512, 2) void gemm256(
    const unsigned short* __restrict__ Ap, const unsigned short* __restrict__ Wp,
    const float* __restrict__ bias, void* __restrict__ Cptr)
{
    constexpr int N = NDIM;
    constexpr int GN = NDIM / BN;            // 4 col tiles
    // [slot][A|B][f-block(16 rows x 32 cols)][1KB]
    __shared__ alignas(16) unsigned short lds[4][2][16][512];

    const int t    = threadIdx.x;
    const int lane = t & 63;
    const int wid  = t >> 6;                 // 0..7
    const int wm   = wid >> 2;               // 0..1  (128 rows each)
    const int wn   = wid & 3;                // 0..3  (64 cols each)

    // XCD-chunked swizzle (nwg = 1024, % 8 == 0)
    const int nwg  = gridDim.x;
    const int cpx  = nwg >> 3;
    const int orig = blockIdx.x;
    const int wgid = (orig & 7) * cpx + (orig >> 3);
    const int bn0  = (wgid & (GN - 1)) * BN;
    const int bm0  = (wgid / GN) * BM;

    // per-lane fragment offset within a block's 16-row x 32-col source region
    const size_t aoff = (size_t)(lane & 15) * KDIM + (lane >> 4) * 8;

#define LDA_(S, MI) \
    (*reinterpret_cast<const short8*>(&lds[S][0][wm * 8 + (MI)][lane * 8]))
#define LDB_(S, NI) \
    (*reinterpret_cast<const short8*>(&lds[S][1][wn * 4 + (NI)][lane * 8]))

    // stage K-tile TAU (A and B) into ring slot SLOT: 4 gloads/wave
#define STAGE_(TAU, SLOT) do {                                                  \
        int _tc = (TAU) < NT ? (TAU) : NT - 1;  /* tail clamp */                \
        _Pragma("unroll")                                                       \
        for (int _ab = 0; _ab < 2; ++_ab) {                                     \
            const unsigned short* _b = _ab ? Wp : Ap;                           \
            int _r0 = _ab ? bn0 : bm0;                                          \
            _Pragma("unroll")                                                   \
            for (int _j = 0; _j < 2; ++_j) {                                    \
                int _f = wid * 2 + _j;                                          \
                gload16(_b + (size_t)(_r0 + _f * 16) * KDIM + _tc * BK + aoff,  \
                        &lds[SLOT][_ab][_f][0]);                                \
            }                                                                   \
        }                                                                       \
    } while (0)

    f32x4 acc[8][4];
#pragma unroll
    for (int mi = 0; mi < 8; ++mi)
#pragma unroll
        for (int ni = 0; ni < 4; ++ni)
            acc[mi][ni] = (f32x4){0.f, 0.f, 0.f, 0.f};

    // prologue: stage tiles 0,1,2 (12 gloads/wave in flight)
    STAGE_(0, 0); STAGE_(1, 1); STAGE_(2, 2);

#pragma unroll 1
    for (int tt = 0; tt < NT; ++tt) {
        const int slot = tt & 3;
        STAGE_(tt + 3, (tt + 3) & 3);
        asm volatile("s_waitcnt vmcnt(12)" ::: "memory");  // stage(tt) landed
        __builtin_amdgcn_s_barrier();

        short8 af[8], bq[4];
#pragma unroll
        for (int mi = 0; mi < 8; ++mi) af[mi] = LDA_(slot, mi);
#pragma unroll
        for (int ni = 0; ni < 4; ++ni) bq[ni] = LDB_(slot, ni);
        __builtin_amdgcn_s_setprio(1);
#pragma unroll
        for (int mi = 0; mi < 8; ++mi)
#pragma unroll
            for (int ni = 0; ni < 4; ++ni)
                acc[mi][ni] = __builtin_amdgcn_mfma_f32_16x16x32_bf16(
                    af[mi], bq[ni], acc[mi][ni], 0, 0, 0);
        __builtin_amdgcn_s_setprio(0);
        __builtin_amdgcn_s_barrier();   // slot reads consumed before reuse
    }

    // drain tail gloads before LDS reuse / endpgm
    asm volatile("s_waitcnt vmcnt(0)" ::: "memory");
    __builtin_amdgcn_s_barrier();

    // ------------- epilogue: LDS bounce -> coalesced full-line stores -------
    // acc fragment: D row = (lane>>4)*4 + r, col = lane&15  [m89-verified]
    const int crow = (lane >> 4) * 4;
    const int ccol = lane & 15;

    if (OUT_F32) {
        float* Cf = (float*)Cptr;
        float* bbf = reinterpret_cast<float*>(&lds[0][0][0][0]);
        float bv[4];
#pragma unroll
        for (int ni = 0; ni < 4; ++ni)
            bv[ni] = bias[bn0 + wn * 64 + ni * 16 + ccol];
        // 4 passes x 64 rows; stride 268 floats (64*268*4 = 68.6 KB in LDS)
#pragma unroll
        for (int p = 0; p < 4; ++p) {
            if (wm == (p >> 1)) {
#pragma unroll
                for (int ml = 0; ml < 4; ++ml)
#pragma unroll
                    for (int ni = 0; ni < 4; ++ni)
#pragma unroll
                        for (int r = 0; r < 4; ++r)
                            bbf[(ml * 16 + crow + r) * 268 + wn * 64 + ni * 16 + ccol]
                                = acc[(p & 1) * 4 + ml][ni][r] + bv[ni];
            }
            __syncthreads();
#pragma unroll
            for (int it = 0; it < 8; ++it) {
                int lrow = wid * 8 + it;                      // 0..63
                f32x4 v = *reinterpret_cast<const f32x4*>(&bbf[lrow * 268 + lane * 4]);
                *reinterpret_cast<f32x4*>(
                    &Cf[(size_t)(bm0 + p * 64 + lrow) * N + bn0 + lane * 4]) = v;
            }
            __syncthreads();
        }
    } else {
        unsigned short* Cb = (unsigned short*)Cptr;
        unsigned short* bb = &lds[0][0][0][0];
        // 2 passes x 128 rows; stride 264 shorts (128*264*2 = 67.6 KB in LDS)
#pragma unroll
        for (int p = 0; p < 2; ++p) {
            if (wm == p) {
#pragma unroll
                for (int ml = 0; ml < 8; ++ml)
#pragma unroll
                    for (int ni = 0; ni < 4; ++ni)
#pragma unroll
                        for (int r = 0; r < 4; ++r)
                            bb[(ml * 16 + crow + r) * 264 + wn * 64 + ni * 16 + ccol]
                                = f2bf(acc[ml][ni][r]);
            }
            __syncthreads();
#pragma unroll
            for (int it = 0; it < 8; ++it) {
                int lrow = wid * 16 + it * 2 + (lane >> 5);   // 0..127
                int lcol = (lane & 31) * 8;                   // 0..255 (tile cols)
                ushort8v v = *reinterpret_cast<const ushort8v*>(&bb[lrow * 264 + lcol]);
                *reinterpret_cast<ushort8v*>(
                    &Cb[(size_t)(bm0 + p * 128 + lrow) * N + bn0 + lcol]) = v;
            }
            __syncthreads();
        }
    }
#undef LDA_
#undef LDB_
#undef STAGE_
}

// ---------------------------------------------------------------------------
// Per-row attention (unchanged, verified): 1 wave/row, 4 waves/block.
// ---------------------------------------------------------------------------
__global__ __launch_bounds__(256) void attn_k(
    const unsigned short* __restrict__ Qb, const unsigned short* __restrict__ Kb,
    const unsigned short* __restrict__ Vb, unsigned short* __restrict__ Fb)
{
    __shared__ alignas(16) unsigned short KL[4][1024];
    __shared__ alignas(16) unsigned short VL[4][1024];
    const int t = threadIdx.x;
    const int lane = t & 63;
    const int wid = t >> 6;
    const size_t row = (size_t)blockIdx.x * 4 + wid;
    const size_t base = row * 1024;
    const int off = lane * 16;

    ushort8v q0 = *reinterpret_cast<const ushort8v*>(&Qb[base + off]);
    ushort8v q1 = *reinterpret_cast<const ushort8v*>(&Qb[base + off + 8]);
    float qf[16];
#pragma unroll
    for (int j = 0; j < 8; ++j) { qf[j] = bf2f(q0[j]); qf[8 + j] = bf2f(q1[j]); }

    *reinterpret_cast<ushort8v*>(&KL[wid][off])     = *reinterpret_cast<const ushort8v*>(&Kb[base + off]);
    *reinterpret_cast<ushort8v*>(&KL[wid][off + 8]) = *reinterpret_cast<const ushort8v*>(&Kb[base + off + 8]);
    *reinterpret_cast<ushort8v*>(&VL[wid][off])     = *reinterpret_cast<const ushort8v*>(&Vb[base + off]);
    *reinterpret_cast<ushort8v*>(&VL[wid][off + 8]) = *reinterpret_cast<const ushort8v*>(&Vb[base + off + 8]);
    __syncthreads();

    const int sub = lane & 3;
    float s[16];
#pragma unroll
    for (int g = 0; g < 16; ++g) {
        const ushort8v k0 = *reinterpret_cast<const ushort8v*>(&KL[wid][g * 64 + sub * 16]);
        const ushort8v k1 = *reinterpret_cast<const ushort8v*>(&KL[wid][g * 64 + sub * 16 + 8]);
        float acc = 0.f;
#pragma unroll
        for (int j = 0; j < 8; ++j)
            acc += qf[j] * bf2f(k0[j]) + qf[8 + j] * bf2f(k1[j]);
        s[g] = acc;
    }
#pragma unroll
    for (int m = 1; m <= 2; m <<= 1)
#pragma unroll
        for (int g = 0; g < 16; ++g)
            s[g] += __shfl_xor(s[g], m, 64);

    float mx = s[0];
#pragma unroll
    for (int g = 1; g < 16; ++g) mx = fmaxf(mx, s[g]);
    float p[16], denom = 0.f;
#pragma unroll
    for (int g = 0; g < 16; ++g) {
        p[g] = __expf((s[g] - mx) * 0.125f);
        denom += p[g];
    }
    float inv = 1.f / denom;

    float f[16];
#pragma unroll
    for (int j = 0; j < 16; ++j) f[j] = 0.f;
#pragma unroll
    for (int g = 0; g < 16; ++g) {
        float pg = p[g] * inv;
        const ushort8v v0 = *reinterpret_cast<const ushort8v*>(&VL[wid][g * 64 + sub * 16]);
        const ushort8v v1 = *reinterpret_cast<const ushort8v*>(&VL[wid][g * 64 + sub * 16 + 8]);
#pragma unroll
        for (int j = 0; j < 8; ++j) {
            f[j]     += pg * bf2f(v0[j]);
            f[8 + j] += pg * bf2f(v1[j]);
        }
    }
    ushort8v o0, o1;
#pragma unroll
    for (int j = 0; j < 8; ++j) { o0[j] = f2bf(f[j]); o1[j] = f2bf(f[8 + j]); }
    *reinterpret_cast<ushort8v*>(&Fb[base + off])     = o0;
    *reinterpret_cast<ushort8v*>(&Fb[base + off + 8]) = o1;
}

// ---------------------------------------------------------------------------
extern "C" void kernel_launch(void* const* d_in, const int* in_sizes, int n_in,
                              void* d_out, int out_size, void* d_ws, size_t ws_size,
                              hipStream_t stream)
{
    (void)in_sizes; (void)n_in; (void)out_size; (void)ws_size;
    const float* latent = (const float*)d_in[0];
    const float* cond   = (const float*)d_in[1];
    const float* Wq     = (const float*)d_in[2];
    const float* Wk     = (const float*)d_in[3];
    const float* Wv     = (const float*)d_in[4];
    const float* Wout   = (const float*)d_in[5];
    const float* bout   = (const float*)d_in[6];
    float* out = (float*)d_out;

    char* ws = (char*)d_ws;
    const size_t MB = 1ull << 20;
    unsigned short* wqb = (unsigned short*)(ws + 0 * MB);
    unsigned short* wkb = (unsigned short*)(ws + 2 * MB);
    unsigned short* wvb = (unsigned short*)(ws + 4 * MB);
    unsigned short* wob = (unsigned short*)(ws + 6 * MB);
    unsigned short* Qb  = (unsigned short*)(ws + 8 * MB);              // 128 MB, becomes feats
    unsigned short* Kbf = (unsigned short*)(ws + 8 * MB + 128 * MB);   // 128 MB
    unsigned short* Vbf = (unsigned short*)(ws + 8 * MB + 256 * MB);   // 128 MB
    unsigned short* Lb  = (unsigned short*)(ws + 8 * MB + 384 * MB);   // 128 MB latent bf16
    unsigned short* Cb  = (unsigned short*)(ws + 8 * MB + 512 * MB);   // 128 MB cond bf16

    const int wn4 = (KDIM * NDIM) / 4;
    f32_to_bf16_k<<<1024, 256, 0, stream>>>(Wq,   wqb, wn4);
    f32_to_bf16_k<<<1024, 256, 0, stream>>>(Wk,   wkb, wn4);
    f32_to_bf16_k<<<1024, 256, 0, stream>>>(Wv,   wvb, wn4);
    f32_to_bf16_k<<<1024, 256, 0, stream>>>(Wout, wob, wn4);

    const int an4 = (NB * KDIM) / 4;
    f32_to_bf16_k<<<4096, 256, 0, stream>>>(latent, Lb, an4);
    f32_to_bf16_k<<<4096, 256, 0, stream>>>(cond,   Cb, an4);

    const int nblk = (NB / BM) * (NDIM / BN);   // 256 * 4 = 1024
    gemm256<0><<<nblk, 512, 0, stream>>>(Lb, wqb, nullptr, Qb);
    gemm256<0><<<nblk, 512, 0, stream>>>(Cb, wkb, nullptr, Kbf);
    gemm256<0><<<nblk, 512, 0, stream>>>(Cb, wvb, nullptr, Vbf);

    attn_k<<<NB / 4, 256, 0, stream>>>(Qb, Kbf, Vbf, Qb);

    gemm256<1><<<nblk, 512, 0, stream>>>(Qb, wob, bout, out);
}